// Round 1
// baseline (1282.637 us; speedup 1.0000x reference)
//
#include <hip/hip_runtime.h>

// Problem constants (from reference)
constexpr int N   = 50000;
constexpr int E   = 800000;
constexpr int FIN = 512;
constexpr int H1v = 256;
constexpr int H2v = 32;
constexpr int Cv  = 16;

// ---------------- degree / normalization ----------------

__global__ __launch_bounds__(256) void k_deg_init(float* __restrict__ deg) {
    int i = blockIdx.x * 256 + threadIdx.x;
    if (i < N) deg[i] = 1.0f;  // self-loop
}

__global__ __launch_bounds__(256) void k_deg_count(const int* __restrict__ dst,
                                                   float* __restrict__ deg) {
    int e = blockIdx.x * 256 + threadIdx.x;
    if (e < E) atomicAdd(&deg[dst[e]], 1.0f);
}

__global__ __launch_bounds__(256) void k_dinv(float* __restrict__ deg) {
    int i = blockIdx.x * 256 + threadIdx.x;
    if (i < N) deg[i] = rsqrtf(deg[i]);  // deg >= 1 always
}

// ---------------- GEMM 1: [N,512] @ [512,256] ----------------
// 64x64 output tile per block, 256 threads, 4x4 microtile, BK=16.

__global__ __launch_bounds__(256) void k_gemm1(const float* __restrict__ X,
                                               const float* __restrict__ W,
                                               float* __restrict__ Hout) {
    __shared__ float As[64][17];  // +1 pad breaks 4-way bank conflict on compute reads
    __shared__ float Bs[16][64];

    const int tid  = threadIdx.x;
    const int tx   = tid & 15;   // col group (4 cols)
    const int ty   = tid >> 4;   // row group (4 rows)
    const int row0 = blockIdx.x * 64;
    const int col0 = blockIdx.y * 64;

    const int lm = tid >> 2;         // A-load row 0..63
    const int lk = (tid & 3) * 4;    // A-load k offset 0/4/8/12
    const int bk = tid >> 4;         // B-load k 0..15
    const int bn = (tid & 15) * 4;   // B-load col*4

    float acc[4][4] = {};

    for (int k0 = 0; k0 < FIN; k0 += 16) {
        int arow = row0 + lm;
        float4 av = make_float4(0.f, 0.f, 0.f, 0.f);
        if (arow < N) av = *(const float4*)(X + (size_t)arow * FIN + k0 + lk);
        As[lm][lk + 0] = av.x; As[lm][lk + 1] = av.y;
        As[lm][lk + 2] = av.z; As[lm][lk + 3] = av.w;

        float4 bv = *(const float4*)(W + (size_t)(k0 + bk) * H1v + col0 + bn);
        *(float4*)(&Bs[bk][bn]) = bv;

        __syncthreads();
#pragma unroll
        for (int k = 0; k < 16; ++k) {
            float a[4], b[4];
#pragma unroll
            for (int i = 0; i < 4; ++i) a[i] = As[ty * 4 + i][k];
#pragma unroll
            for (int j = 0; j < 4; ++j) b[j] = Bs[k][tx * 4 + j];
#pragma unroll
            for (int i = 0; i < 4; ++i)
#pragma unroll
                for (int j = 0; j < 4; ++j)
                    acc[i][j] = fmaf(a[i], b[j], acc[i][j]);
        }
        __syncthreads();
    }

#pragma unroll
    for (int i = 0; i < 4; ++i) {
        int r = row0 + ty * 4 + i;
        if (r < N) {
            float4 v = make_float4(acc[i][0], acc[i][1], acc[i][2], acc[i][3]);
            *(float4*)(Hout + (size_t)r * H1v + col0 + tx * 4) = v;
        }
    }
}

// ---------------- GEMM 2: [N,256] @ [256,32] ----------------
// W2 (32 KB) fully in LDS; 8 rows per block, 32 cols per row.

__global__ __launch_bounds__(256) void k_gemm2(const float* __restrict__ A,
                                               const float* __restrict__ W,
                                               float* __restrict__ Hout) {
    __shared__ float Ws[H1v * H2v];  // 8192 floats = 32 KB
    const int tid = threadIdx.x;
#pragma unroll
    for (int i = 0; i < 8; ++i) {
        int off = tid * 4 + i * 1024;
        *(float4*)(&Ws[off]) = *(const float4*)(W + off);
    }
    __syncthreads();

    const int row = blockIdx.x * 8 + (tid >> 5);
    const int col = tid & 31;
    if (row >= N) return;
    const float* arow = A + (size_t)row * H1v;
    float sum = 0.f;
#pragma unroll 4
    for (int k = 0; k < H1v; k += 4) {
        float4 a4 = *(const float4*)(arow + k);
        sum = fmaf(a4.x, Ws[(k + 0) * H2v + col], sum);
        sum = fmaf(a4.y, Ws[(k + 1) * H2v + col], sum);
        sum = fmaf(a4.z, Ws[(k + 2) * H2v + col], sum);
        sum = fmaf(a4.w, Ws[(k + 3) * H2v + col], sum);
    }
    Hout[(size_t)row * H2v + col] = sum;
}

// ---------------- GEMM 3: [N,32] @ [32,16] ----------------

__global__ __launch_bounds__(256) void k_gemm3(const float* __restrict__ A,
                                               const float* __restrict__ W,
                                               float* __restrict__ Hout) {
    __shared__ float Ws[H2v * Cv];  // 512 floats
    const int tid = threadIdx.x;
    *(float2*)(&Ws[tid * 2]) = *(const float2*)(W + tid * 2);
    __syncthreads();

    const int row = blockIdx.x * 16 + (tid >> 4);
    const int col = tid & 15;
    if (row >= N) return;
    const float* arow = A + (size_t)row * H2v;
    float sum = 0.f;
#pragma unroll
    for (int k = 0; k < H2v; ++k) sum = fmaf(arow[k], Ws[k * Cv + col], sum);
    Hout[(size_t)row * Cv + col] = sum;
}

// ---------------- scatter-add (edge propagation) ----------------

__global__ __launch_bounds__(256) void k_scatter_d256(const float* __restrict__ h,
                                                      const int* __restrict__ src,
                                                      const int* __restrict__ dst,
                                                      const float* __restrict__ dinv,
                                                      float* __restrict__ out) {
    const int e = blockIdx.x;  // one edge per block, 256 dims
    const int s = src[e], d = dst[e];
    const float w = dinv[s] * dinv[d];
    const int j = threadIdx.x;
    atomicAdd(out + (size_t)d * 256 + j, h[(size_t)s * 256 + j] * w);
}

__global__ __launch_bounds__(256) void k_scatter_d32(const float* __restrict__ h,
                                                     const int* __restrict__ src,
                                                     const int* __restrict__ dst,
                                                     const float* __restrict__ dinv,
                                                     float* __restrict__ out) {
    const int e = blockIdx.x * 8 + (threadIdx.x >> 5);  // 8 edges per block
    const int j = threadIdx.x & 31;
    const int s = src[e], d = dst[e];
    const float w = dinv[s] * dinv[d];
    atomicAdd(out + (size_t)d * 32 + j, h[(size_t)s * 32 + j] * w);
}

__global__ __launch_bounds__(256) void k_scatter_d16(const float* __restrict__ h,
                                                     const int* __restrict__ src,
                                                     const int* __restrict__ dst,
                                                     const float* __restrict__ dinv,
                                                     float* __restrict__ out) {
    const int e = blockIdx.x * 16 + (threadIdx.x >> 4);  // 16 edges per block
    const int j = threadIdx.x & 15;
    const int s = src[e], d = dst[e];
    const float w = dinv[s] * dinv[d];
    atomicAdd(out + (size_t)d * 16 + j, h[(size_t)s * 16 + j] * w);
}

// ---------------- epilogue: self-loop + bias (+ ReLU) ----------------

template <int D, int SHIFT, bool RELU>
__global__ __launch_bounds__(256) void k_finalize(float* __restrict__ agg,
                                                  const float* __restrict__ h,
                                                  const float* __restrict__ dinv,
                                                  const float* __restrict__ bias) {
    int idx = blockIdx.x * 256 + threadIdx.x;
    if (idx >= N * D) return;
    int i = idx >> SHIFT;
    int j = idx & (D - 1);
    float di = dinv[i];
    float v = agg[idx] + h[idx] * di * di + bias[j];
    if (RELU) v = fmaxf(v, 0.f);
    agg[idx] = v;
}

// ---------------- launch ----------------

extern "C" void kernel_launch(void* const* d_in, const int* in_sizes, int n_in,
                              void* d_out, int out_size, void* d_ws, size_t ws_size,
                              hipStream_t stream) {
    const float* x  = (const float*)d_in[0];
    const int*   ei = (const int*)d_in[1];
    const float* W1 = (const float*)d_in[2];
    const float* b1 = (const float*)d_in[3];
    const float* W2 = (const float*)d_in[4];
    const float* b2 = (const float*)d_in[5];
    const float* W3 = (const float*)d_in[6];
    const float* b3 = (const float*)d_in[7];
    const int* src = ei;       // edge_index[0]
    const int* dst = ei + E;   // edge_index[1]
    float* out = (float*)d_out;

    // Workspace layout: [dinv 1MB][hbuf 50MiB][abuf 50MiB]  (~101 MiB total)
    char* ws = (char*)d_ws;
    float* dinv = (float*)ws;
    float* hbuf = (float*)(ws + (1 << 20));
    float* abuf = (float*)(ws + (1 << 20) + (size_t)50 * (1 << 20));

    // normalization
    k_deg_init<<<(N + 255) / 256, 256, 0, stream>>>(dinv);
    k_deg_count<<<(E + 255) / 256, 256, 0, stream>>>(dst, dinv);
    k_dinv<<<(N + 255) / 256, 256, 0, stream>>>(dinv);

    // ---- layer 1: 512 -> 256, ReLU ----
    dim3 g1((N + 63) / 64, H1v / 64);
    k_gemm1<<<g1, 256, 0, stream>>>(x, W1, hbuf);
    hipMemsetAsync(abuf, 0, (size_t)N * H1v * sizeof(float), stream);
    k_scatter_d256<<<E, 256, 0, stream>>>(hbuf, src, dst, dinv, abuf);
    k_finalize<256, 8, true><<<(N * H1v + 255) / 256, 256, 0, stream>>>(abuf, hbuf, dinv, b1);

    // ---- layer 2: 256 -> 32, ReLU ----
    k_gemm2<<<N / 8, 256, 0, stream>>>(abuf, W2, hbuf);
    hipMemsetAsync(abuf, 0, (size_t)N * H2v * sizeof(float), stream);
    k_scatter_d32<<<E / 8, 256, 0, stream>>>(hbuf, src, dst, dinv, abuf);
    k_finalize<32, 5, true><<<(N * H2v + 255) / 256, 256, 0, stream>>>(abuf, hbuf, dinv, b2);

    // ---- layer 3: 32 -> 16, no ReLU ----
    k_gemm3<<<N / 16, 256, 0, stream>>>(abuf, W3, hbuf);
    hipMemsetAsync(out, 0, (size_t)N * Cv * sizeof(float), stream);
    k_scatter_d16<<<E / 16, 256, 0, stream>>>(hbuf, src, dst, dinv, out);
    k_finalize<16, 4, false><<<(N * Cv + 255) / 256, 256, 0, stream>>>(out, hbuf, dinv, b3);
}

// Round 2
// 735.242 us; speedup vs baseline: 1.7445x; 1.7445x over previous
//
#include <hip/hip_runtime.h>

// Problem constants (from reference)
constexpr int N   = 50000;
constexpr int E   = 800000;
constexpr int FIN = 512;
constexpr int H1v = 256;
constexpr int H2v = 32;
constexpr int Cv  = 16;

// ---------------- degree histogram / normalization ----------------

__global__ __launch_bounds__(256) void k_hist(const int* __restrict__ dst,
                                              int* __restrict__ cnt) {
    int e = blockIdx.x * 256 + threadIdx.x;
    if (e < E) atomicAdd(&cnt[dst[e]], 1);
}

__global__ __launch_bounds__(256) void k_dinv(const int* __restrict__ cnt,
                                              float* __restrict__ dinv) {
    int i = blockIdx.x * 256 + threadIdx.x;
    if (i < N) dinv[i] = rsqrtf(1.0f + (float)cnt[i]);  // +1 self-loop
}

// Single-block exclusive scan over 50000 counts -> row_ptr and cursor copies.
__global__ __launch_bounds__(1024) void k_scan(const int* __restrict__ cnt,
                                               int* __restrict__ row_ptr,
                                               int* __restrict__ cursor) {
    __shared__ int sums[1024];
    const int t = threadIdx.x;
    constexpr int CH = 49;  // 1024*49 = 50176 >= N
    const int base = t * CH;
    int vals[CH];
    int local = 0;
#pragma unroll
    for (int i = 0; i < CH; ++i) {
        int idx = base + i;
        int v = (idx < N) ? cnt[idx] : 0;
        vals[i] = v;
        local += v;
    }
    sums[t] = local;
    __syncthreads();
    for (int off = 1; off < 1024; off <<= 1) {
        int v = (t >= off) ? sums[t - off] : 0;
        __syncthreads();
        sums[t] += v;
        __syncthreads();
    }
    int run = (t == 0) ? 0 : sums[t - 1];
#pragma unroll
    for (int i = 0; i < CH; ++i) {
        int idx = base + i;
        if (idx < N) { row_ptr[idx] = run; cursor[idx] = run; }
        run += vals[i];
    }
    if (t == 1023) row_ptr[N] = run;  // == E
}

__global__ __launch_bounds__(256) void k_permute(const int* __restrict__ src,
                                                 const int* __restrict__ dst,
                                                 int* __restrict__ cursor,
                                                 int* __restrict__ srcs) {
    int e = blockIdx.x * 256 + threadIdx.x;
    if (e < E) {
        int pos = atomicAdd(&cursor[dst[e]], 1);
        srcs[pos] = src[e];
    }
}

// ---------------- GEMM 1: [N,512] @ [512,256], epilogue *dinv[row] ----------------

__global__ __launch_bounds__(256) void k_gemm1(const float* __restrict__ X,
                                               const float* __restrict__ W,
                                               const float* __restrict__ dinv,
                                               float* __restrict__ Hout) {
    __shared__ float As[64][17];
    __shared__ float Bs[16][64];

    const int tid  = threadIdx.x;
    const int tx   = tid & 15;
    const int ty   = tid >> 4;
    const int row0 = blockIdx.x * 64;
    const int col0 = blockIdx.y * 64;

    const int lm = tid >> 2;
    const int lk = (tid & 3) * 4;
    const int bk = tid >> 4;
    const int bn = (tid & 15) * 4;

    float acc[4][4] = {};

    for (int k0 = 0; k0 < FIN; k0 += 16) {
        int arow = row0 + lm;
        float4 av = make_float4(0.f, 0.f, 0.f, 0.f);
        if (arow < N) av = *(const float4*)(X + (size_t)arow * FIN + k0 + lk);
        As[lm][lk + 0] = av.x; As[lm][lk + 1] = av.y;
        As[lm][lk + 2] = av.z; As[lm][lk + 3] = av.w;

        float4 bv = *(const float4*)(W + (size_t)(k0 + bk) * H1v + col0 + bn);
        *(float4*)(&Bs[bk][bn]) = bv;

        __syncthreads();
#pragma unroll
        for (int k = 0; k < 16; ++k) {
            float a[4], b[4];
#pragma unroll
            for (int i = 0; i < 4; ++i) a[i] = As[ty * 4 + i][k];
#pragma unroll
            for (int j = 0; j < 4; ++j) b[j] = Bs[k][tx * 4 + j];
#pragma unroll
            for (int i = 0; i < 4; ++i)
#pragma unroll
                for (int j = 0; j < 4; ++j)
                    acc[i][j] = fmaf(a[i], b[j], acc[i][j]);
        }
        __syncthreads();
    }

#pragma unroll
    for (int i = 0; i < 4; ++i) {
        int r = row0 + ty * 4 + i;
        if (r < N) {
            float di = dinv[r];
            float4 v = make_float4(acc[i][0] * di, acc[i][1] * di,
                                   acc[i][2] * di, acc[i][3] * di);
            *(float4*)(Hout + (size_t)r * H1v + col0 + tx * 4) = v;
        }
    }
}

// ---------------- GEMM 2: [N,256] @ [256,32], epilogue *dinv[row] ----------------

__global__ __launch_bounds__(256) void k_gemm2(const float* __restrict__ A,
                                               const float* __restrict__ W,
                                               const float* __restrict__ dinv,
                                               float* __restrict__ Hout) {
    __shared__ float Ws[H1v * H2v];  // 32 KB
    const int tid = threadIdx.x;
#pragma unroll
    for (int i = 0; i < 8; ++i) {
        int off = tid * 4 + i * 1024;
        *(float4*)(&Ws[off]) = *(const float4*)(W + off);
    }
    __syncthreads();

    const int row = blockIdx.x * 8 + (tid >> 5);
    const int col = tid & 31;
    if (row >= N) return;
    const float* arow = A + (size_t)row * H1v;
    float sum = 0.f;
#pragma unroll 4
    for (int k = 0; k < H1v; k += 4) {
        float4 a4 = *(const float4*)(arow + k);
        sum = fmaf(a4.x, Ws[(k + 0) * H2v + col], sum);
        sum = fmaf(a4.y, Ws[(k + 1) * H2v + col], sum);
        sum = fmaf(a4.z, Ws[(k + 2) * H2v + col], sum);
        sum = fmaf(a4.w, Ws[(k + 3) * H2v + col], sum);
    }
    Hout[(size_t)row * H2v + col] = sum * dinv[row];
}

// ---------------- GEMM 3: [N,32] @ [32,16], epilogue *dinv[row] ----------------

__global__ __launch_bounds__(256) void k_gemm3(const float* __restrict__ A,
                                               const float* __restrict__ W,
                                               const float* __restrict__ dinv,
                                               float* __restrict__ Hout) {
    __shared__ float Ws[H2v * Cv];
    const int tid = threadIdx.x;
    *(float2*)(&Ws[tid * 2]) = *(const float2*)(W + tid * 2);
    __syncthreads();

    const int row = blockIdx.x * 16 + (tid >> 4);
    const int col = tid & 15;
    if (row >= N) return;
    const float* arow = A + (size_t)row * H2v;
    float sum = 0.f;
#pragma unroll
    for (int k = 0; k < H2v; ++k) sum = fmaf(arow[k], Ws[k * Cv + col], sum);
    Hout[(size_t)row * Cv + col] = sum * dinv[row];
}

// ---------------- CSR aggregation (atomic-free) ----------------
// h holds h'[i] = dinv[i] * (a @ W)[i].  out[d] = dinv[d]*(sum_{s in N(d)} h'[s] + h'[d]) + b

__global__ __launch_bounds__(256) void k_agg_d256(const float* __restrict__ h,
                                                  const int* __restrict__ rp,
                                                  const int* __restrict__ srcs,
                                                  const float* __restrict__ dinv,
                                                  const float* __restrict__ bias,
                                                  float* __restrict__ out) {
    const int wave = threadIdx.x >> 6;
    const int lane = threadIdx.x & 63;
    const int d = blockIdx.x * 4 + wave;
    if (d >= N) return;
    const int beg = rp[d], end = rp[d + 1];
    const int fo = lane * 4;
    float4 acc = *(const float4*)(h + (size_t)d * H1v + fo);  // self-loop
    for (int j = beg; j < end; ++j) {
        const int s = srcs[j];
        const float4 v = *(const float4*)(h + (size_t)s * H1v + fo);
        acc.x += v.x; acc.y += v.y; acc.z += v.z; acc.w += v.w;
    }
    const float di = dinv[d];
    const float4 b4 = *(const float4*)(bias + fo);
    float4 o;
    o.x = fmaxf(fmaf(di, acc.x, b4.x), 0.f);
    o.y = fmaxf(fmaf(di, acc.y, b4.y), 0.f);
    o.z = fmaxf(fmaf(di, acc.z, b4.z), 0.f);
    o.w = fmaxf(fmaf(di, acc.w, b4.w), 0.f);
    *(float4*)(out + (size_t)d * H1v + fo) = o;
}

template <int D, bool RELU>
__global__ __launch_bounds__(256) void k_agg_small(const float* __restrict__ h,
                                                   const int* __restrict__ rp,
                                                   const int* __restrict__ srcs,
                                                   const float* __restrict__ dinv,
                                                   const float* __restrict__ bias,
                                                   float* __restrict__ out) {
    constexpr int PER = 256 / D;
    const int sub = threadIdx.x / D;
    const int f = threadIdx.x % D;
    const int d = blockIdx.x * PER + sub;
    if (d >= N) return;
    const int beg = rp[d], end = rp[d + 1];
    float acc = h[(size_t)d * D + f];  // self-loop
    for (int j = beg; j < end; ++j) acc += h[(size_t)srcs[j] * D + f];
    float v = fmaf(dinv[d], acc, bias[f]);
    if (RELU) v = fmaxf(v, 0.f);
    out[(size_t)d * D + f] = v;
}

// ---------------- launch ----------------

extern "C" void kernel_launch(void* const* d_in, const int* in_sizes, int n_in,
                              void* d_out, int out_size, void* d_ws, size_t ws_size,
                              hipStream_t stream) {
    const float* x  = (const float*)d_in[0];
    const int*   ei = (const int*)d_in[1];
    const float* W1 = (const float*)d_in[2];
    const float* b1 = (const float*)d_in[3];
    const float* W2 = (const float*)d_in[4];
    const float* b2 = (const float*)d_in[5];
    const float* W3 = (const float*)d_in[6];
    const float* b3 = (const float*)d_in[7];
    const int* src = ei;       // edge_index[0]
    const int* dst = ei + E;   // edge_index[1]
    float* out = (float*)d_out;

    // Workspace layout (bytes):
    // [0       ] dinv   float[50000]   (200 KB)
    // [0x40000 ] cnt / row_ptr int[50001]
    // [0x80000 ] cursor int[50000]
    // [0xC0000 ] srcs   int[800000]    (3.2 MB)
    // [4 MiB   ] hbuf   float[N*256]   (51.2 MB)
    // [~56.8MiB] abuf   float[N*256]   (51.2 MB)
    char* ws = (char*)d_ws;
    float* dinv  = (float*)ws;
    int*   cnt   = (int*)(ws + 0x40000);   // reused as row_ptr after scan? no: scan reads cnt, writes rp
    int*   rp    = cnt;                    // row_ptr overwrites cnt in-place is NOT safe; see below
    int*   cursor= (int*)(ws + 0x80000);
    int*   srcs  = (int*)(ws + 0xC0000);
    float* hbuf  = (float*)(ws + (size_t)4 * 1024 * 1024);
    float* abuf  = (float*)(ws + (size_t)4 * 1024 * 1024 + (size_t)N * H1v * sizeof(float));

    // NOTE on cnt/rp aliasing: k_scan reads cnt[] sequentially into registers
    // (vals[]) BEFORE writing row_ptr[]; within one thread's chunk the reads all
    // complete before its writes, and each index is touched by exactly one
    // thread for both read and write, so in-place exclusive scan is safe here.

    hipMemsetAsync(cnt, 0, (N + 1) * sizeof(int), stream);
    k_hist<<<(E + 255) / 256, 256, 0, stream>>>(dst, cnt);
    k_dinv<<<(N + 255) / 256, 256, 0, stream>>>(cnt, dinv);
    k_scan<<<1, 1024, 0, stream>>>(cnt, rp, cursor);
    k_permute<<<(E + 255) / 256, 256, 0, stream>>>(src, dst, cursor, srcs);

    // ---- layer 1: 512 -> 256, ReLU ----
    dim3 g1((N + 63) / 64, H1v / 64);
    k_gemm1<<<g1, 256, 0, stream>>>(x, W1, dinv, hbuf);
    k_agg_d256<<<(N + 3) / 4, 256, 0, stream>>>(hbuf, rp, srcs, dinv, b1, abuf);

    // ---- layer 2: 256 -> 32, ReLU ----
    k_gemm2<<<N / 8, 256, 0, stream>>>(abuf, W2, dinv, hbuf);
    k_agg_small<32, true><<<N / 8, 256, 0, stream>>>(hbuf, rp, srcs, dinv, b2, abuf);

    // ---- layer 3: 32 -> 16, no ReLU ----
    k_gemm3<<<N / 16, 256, 0, stream>>>(abuf, W3, dinv, hbuf);
    k_agg_small<16, false><<<N / 16, 256, 0, stream>>>(hbuf, rp, srcs, dinv, b3, out);
}

// Round 3
// 600.418 us; speedup vs baseline: 2.1362x; 1.2245x over previous
//
#include <hip/hip_runtime.h>

// Problem constants (from reference)
constexpr int N   = 50000;
constexpr int E   = 800000;
constexpr int FIN = 512;
constexpr int H1v = 256;
constexpr int H2v = 32;
constexpr int Cv  = 16;

typedef __attribute__((ext_vector_type(8))) short short8;   // 8 bf16 = 4 VGPRs (MFMA A/B frag)
typedef __attribute__((ext_vector_type(4))) float f32x4;    // MFMA C/D frag

// fp32 -> bf16 round-to-nearest-even, and back
__device__ inline unsigned short f2bf(float f) {
    unsigned u = __float_as_uint(f);
    return (unsigned short)((u + 0x7FFFu + ((u >> 16) & 1u)) >> 16);
}
__device__ inline float bf2f(unsigned short b) { return __uint_as_float(((unsigned)b) << 16); }

// ---------------- degree histogram / normalization ----------------

__global__ __launch_bounds__(256) void k_hist(const int* __restrict__ dst,
                                              int* __restrict__ cnt) {
    int e = blockIdx.x * 256 + threadIdx.x;
    if (e < E) atomicAdd(&cnt[dst[e]], 1);
}

__global__ __launch_bounds__(256) void k_dinv(const int* __restrict__ cnt,
                                              float* __restrict__ dinv) {
    int i = blockIdx.x * 256 + threadIdx.x;
    if (i < N) dinv[i] = rsqrtf(1.0f + (float)cnt[i]);  // +1 self-loop
}

// Single-block exclusive scan over 50000 counts -> row_ptr and cursor copies.
// In-place safe: each thread reads its chunk into registers before writing.
__global__ __launch_bounds__(1024) void k_scan(const int* __restrict__ cnt,
                                               int* __restrict__ row_ptr,
                                               int* __restrict__ cursor) {
    __shared__ int sums[1024];
    const int t = threadIdx.x;
    constexpr int CH = 49;  // 1024*49 = 50176 >= N
    const int base = t * CH;
    int vals[CH];
    int local = 0;
#pragma unroll
    for (int i = 0; i < CH; ++i) {
        int idx = base + i;
        int v = (idx < N) ? cnt[idx] : 0;
        vals[i] = v;
        local += v;
    }
    sums[t] = local;
    __syncthreads();
    for (int off = 1; off < 1024; off <<= 1) {
        int v = (t >= off) ? sums[t - off] : 0;
        __syncthreads();
        sums[t] += v;
        __syncthreads();
    }
    int run = (t == 0) ? 0 : sums[t - 1];
#pragma unroll
    for (int i = 0; i < CH; ++i) {
        int idx = base + i;
        if (idx < N) { row_ptr[idx] = run; cursor[idx] = run; }
        run += vals[i];
    }
    if (t == 1023) row_ptr[N] = run;  // == E
}

__global__ __launch_bounds__(256) void k_permute(const int* __restrict__ src,
                                                 const int* __restrict__ dst,
                                                 int* __restrict__ cursor,
                                                 int* __restrict__ srcs) {
    int e = blockIdx.x * 256 + threadIdx.x;
    if (e < E) {
        int pos = atomicAdd(&cursor[dst[e]], 1);
        srcs[pos] = src[e];
    }
}

// ---------------- W1 split: fp32 [512][256] -> bf16 hi/lo in MFMA B-frag layout ----
// Tile (ktg in 0..15, ntg in 0..15): B[k][n], k = ktg*32 + (l>>4)*8 + j, n = ntg*16 + (l&15).
// Storage (ushorts): tile base = ((ktg*16+ntg)*2)*512; hi at +l*8, lo at +512+l*8.

__global__ __launch_bounds__(256) void k_wsplit(const float* __restrict__ W,
                                                unsigned short* __restrict__ Wf) {
    int t = blockIdx.x * 256 + threadIdx.x;  // 0..16383
    int l = t & 63, nt = (t >> 6) & 15, kt = t >> 10;
    int n = nt * 16 + (l & 15);
    int kb = kt * 32 + (l >> 4) * 8;
    short8 h8, l8;
#pragma unroll
    for (int j = 0; j < 8; ++j) {
        float w = W[(size_t)(kb + j) * H1v + n];
        unsigned short h = f2bf(w);
        h8[j] = (short)h;
        l8[j] = (short)f2bf(w - bf2f(h));
    }
    size_t base = ((size_t)(kt * 16 + nt) * 2) * 512 + (size_t)l * 8;
    *(short8*)(Wf + base) = h8;
    *(short8*)(Wf + base + 512) = l8;
}

// ---------------- GEMM 1 (MFMA, split-bf16 x3): [N,512] @ [512,256], *dinv ------
// 128x128 block tile, BK=64, 4 waves at 64x64 quadrants, 16x16x32 bf16 MFMA.
// A (X tile) converted fp32->bf16 hi/lo in-kernel, staged to LDS frag layout.
// B (W1) read from pre-split frag buffer via global_load_lds (width 16).
// LDS layout: A chunk ((kt*8+rt)*2+plane)*1024 + l*16  (32 KB)
//             B chunk 32768 + ((kt*8+nt)*2+plane)*1024 + l*16  (32 KB)

__global__ __launch_bounds__(256, 2) void k_gemm1_mfma(const float* __restrict__ X,
                                                       const unsigned short* __restrict__ Wf,
                                                       const float* __restrict__ dinv,
                                                       float* __restrict__ Hout) {
    __shared__ char lds[65536];
    const int tid = threadIdx.x;
    const int w = tid >> 6, l = tid & 63;
    const int wr = w >> 1, wc = w & 1;
    const int row0 = blockIdx.x * 128;
    const int colb = blockIdx.y;

    // A staging assignment: thread <-> (row_local = tid>>1, k-half = tid&1)
    const int arow_l = tid >> 1;
    const int akh = tid & 1;
    const int arow = row0 + arow_l;
    const bool aok = arow < N;
    const float* aptr = X + (size_t)arow * FIN + akh * 32;
    const int art = arow_l >> 4, am = arow_l & 15;

    f32x4 acc[4][4];
#pragma unroll
    for (int i = 0; i < 4; ++i)
#pragma unroll
        for (int j = 0; j < 4; ++j) acc[i][j] = (f32x4)0.f;

    float4 xv[8];
#pragma unroll
    for (int g = 0; g < 8; ++g)
        xv[g] = aok ? *(const float4*)(aptr + g * 4) : make_float4(0.f, 0.f, 0.f, 0.f);

    for (int it = 0; it < 8; ++it) {  // 512 / 64
        __syncthreads();  // waves done reading LDS from previous iter

        // ---- A: convert 32 fp32 -> bf16 hi/lo, write frag entries ----
#pragma unroll
        for (int g = 0; g < 4; ++g) {
            float xs[8] = {xv[2*g].x, xv[2*g].y, xv[2*g].z, xv[2*g].w,
                           xv[2*g+1].x, xv[2*g+1].y, xv[2*g+1].z, xv[2*g+1].w};
            short8 h8, l8;
#pragma unroll
            for (int j = 0; j < 8; ++j) {
                unsigned short h = f2bf(xs[j]);
                h8[j] = (short)h;
                l8[j] = (short)f2bf(xs[j] - bf2f(h));
            }
            char* pa = lds + ((akh * 8 + art) * 2) * 1024 + (g * 16 + am) * 16;
            *(short8*)pa = h8;
            *(short8*)(pa + 1024) = l8;
        }

        // ---- B: 32 chunks of 1 KB via async global->LDS, 8 per wave ----
#pragma unroll
        for (int c = 0; c < 8; ++c) {
            int chunk = w * 8 + c;
            int plane = chunk & 1, nt = (chunk >> 1) & 7, kt = chunk >> 4;
            int ktg = it * 2 + kt, ntg = colb * 8 + nt;
            const unsigned short* gp = Wf + ((size_t)(ktg * 16 + ntg) * 2 + plane) * 512 + (size_t)l * 8;
            char* lp = lds + 32768 + ((kt * 8 + nt) * 2 + plane) * 1024 + l * 16;
            __builtin_amdgcn_global_load_lds(
                (const __attribute__((address_space(1))) unsigned int*)gp,
                (__attribute__((address_space(3))) unsigned int*)lp, 16, 0, 0);
        }
        __syncthreads();  // implies vmcnt(0): B staged, A visible

        // prefetch next iter's X while MFMAs run
        if (it < 7) {
#pragma unroll
            for (int g = 0; g < 8; ++g)
                xv[g] = aok ? *(const float4*)(aptr + (it + 1) * 64 + g * 4)
                            : make_float4(0.f, 0.f, 0.f, 0.f);
        }

        // ---- MFMA: 2 k-tiles of K=32, 4x4 16x16 tiles, 3 splits ----
#pragma unroll
        for (int kt = 0; kt < 2; ++kt) {
            short8 Ah[4], Al[4], Bh[4], Bl[4];
#pragma unroll
            for (int i = 0; i < 4; ++i) {
                char* p = lds + ((kt * 8 + wr * 4 + i) * 2) * 1024 + l * 16;
                Ah[i] = *(short8*)p;
                Al[i] = *(short8*)(p + 1024);
            }
#pragma unroll
            for (int j = 0; j < 4; ++j) {
                char* p = lds + 32768 + ((kt * 8 + wc * 4 + j) * 2) * 1024 + l * 16;
                Bh[j] = *(short8*)p;
                Bl[j] = *(short8*)(p + 1024);
            }
#pragma unroll
            for (int i = 0; i < 4; ++i)
#pragma unroll
                for (int j = 0; j < 4; ++j) {
                    acc[i][j] = __builtin_amdgcn_mfma_f32_16x16x32_bf16(Ah[i], Bh[j], acc[i][j], 0, 0, 0);
                    acc[i][j] = __builtin_amdgcn_mfma_f32_16x16x32_bf16(Ah[i], Bl[j], acc[i][j], 0, 0, 0);
                    acc[i][j] = __builtin_amdgcn_mfma_f32_16x16x32_bf16(Al[i], Bh[j], acc[i][j], 0, 0, 0);
                }
        }
    }

    // ---- epilogue: C row = (l>>4)*4 + reg, col = l&15 ; scale by dinv[row] ----
    const int col0 = colb * 128;
#pragma unroll
    for (int i = 0; i < 4; ++i) {
        int rbase = row0 + (wr * 4 + i) * 16 + (l >> 4) * 4;
        float dv[4];
        bool ok[4];
#pragma unroll
        for (int r = 0; r < 4; ++r) {
            int rr = rbase + r;
            ok[r] = rr < N;
            dv[r] = ok[r] ? dinv[rr] : 0.f;
        }
#pragma unroll
        for (int j = 0; j < 4; ++j) {
            int col = col0 + (wc * 4 + j) * 16 + (l & 15);
#pragma unroll
            for (int r = 0; r < 4; ++r)
                if (ok[r]) Hout[(size_t)(rbase + r) * H1v + col] = acc[i][j][r] * dv[r];
        }
    }
}

// ---------------- GEMM 2: [N,256] @ [256,32], epilogue *dinv[row] ----------------

__global__ __launch_bounds__(256) void k_gemm2(const float* __restrict__ A,
                                               const float* __restrict__ W,
                                               const float* __restrict__ dinv,
                                               float* __restrict__ Hout) {
    __shared__ float Ws[H1v * H2v];  // 32 KB
    const int tid = threadIdx.x;
#pragma unroll
    for (int i = 0; i < 8; ++i) {
        int off = tid * 4 + i * 1024;
        *(float4*)(&Ws[off]) = *(const float4*)(W + off);
    }
    __syncthreads();

    const int row = blockIdx.x * 8 + (tid >> 5);
    const int col = tid & 31;
    if (row >= N) return;
    const float* arow = A + (size_t)row * H1v;
    float sum = 0.f;
#pragma unroll 4
    for (int k = 0; k < H1v; k += 4) {
        float4 a4 = *(const float4*)(arow + k);
        sum = fmaf(a4.x, Ws[(k + 0) * H2v + col], sum);
        sum = fmaf(a4.y, Ws[(k + 1) * H2v + col], sum);
        sum = fmaf(a4.z, Ws[(k + 2) * H2v + col], sum);
        sum = fmaf(a4.w, Ws[(k + 3) * H2v + col], sum);
    }
    Hout[(size_t)row * H2v + col] = sum * dinv[row];
}

// ---------------- GEMM 3: [N,32] @ [32,16], epilogue *dinv[row] ----------------

__global__ __launch_bounds__(256) void k_gemm3(const float* __restrict__ A,
                                               const float* __restrict__ W,
                                               const float* __restrict__ dinv,
                                               float* __restrict__ Hout) {
    __shared__ float Ws[H2v * Cv];
    const int tid = threadIdx.x;
    *(float2*)(&Ws[tid * 2]) = *(const float2*)(W + tid * 2);
    __syncthreads();

    const int row = blockIdx.x * 16 + (tid >> 4);
    const int col = tid & 15;
    if (row >= N) return;
    const float* arow = A + (size_t)row * H2v;
    float sum = 0.f;
#pragma unroll
    for (int k = 0; k < H2v; ++k) sum = fmaf(arow[k], Ws[k * Cv + col], sum);
    Hout[(size_t)row * Cv + col] = sum * dinv[row];
}

// ---------------- CSR aggregation (atomic-free) ----------------
// h holds h'[i] = dinv[i]*(a@W)[i].  out[d] = dinv[d]*(sum_{s in N(d)} h'[s] + h'[d]) + b

__global__ __launch_bounds__(256) void k_agg_d256(const float* __restrict__ h,
                                                  const int* __restrict__ rp,
                                                  const int* __restrict__ srcs,
                                                  const float* __restrict__ dinv,
                                                  const float* __restrict__ bias,
                                                  float* __restrict__ out) {
    const int wave = threadIdx.x >> 6;
    const int lane = threadIdx.x & 63;
    const int d = blockIdx.x * 4 + wave;
    if (d >= N) return;
    const int beg = rp[d], end = rp[d + 1];
    const int fo = lane * 4;
    float4 acc = *(const float4*)(h + (size_t)d * H1v + fo);  // self-loop
    int j = beg;
    for (; j + 3 < end; j += 4) {  // 4 independent gathers in flight
        int s0 = srcs[j], s1 = srcs[j + 1], s2 = srcs[j + 2], s3 = srcs[j + 3];
        float4 v0 = *(const float4*)(h + (size_t)s0 * H1v + fo);
        float4 v1 = *(const float4*)(h + (size_t)s1 * H1v + fo);
        float4 v2 = *(const float4*)(h + (size_t)s2 * H1v + fo);
        float4 v3 = *(const float4*)(h + (size_t)s3 * H1v + fo);
        acc.x += v0.x + v1.x + v2.x + v3.x;
        acc.y += v0.y + v1.y + v2.y + v3.y;
        acc.z += v0.z + v1.z + v2.z + v3.z;
        acc.w += v0.w + v1.w + v2.w + v3.w;
    }
    for (; j < end; ++j) {
        const float4 v = *(const float4*)(h + (size_t)srcs[j] * H1v + fo);
        acc.x += v.x; acc.y += v.y; acc.z += v.z; acc.w += v.w;
    }
    const float di = dinv[d];
    const float4 b4 = *(const float4*)(bias + fo);
    float4 o;
    o.x = fmaxf(fmaf(di, acc.x, b4.x), 0.f);
    o.y = fmaxf(fmaf(di, acc.y, b4.y), 0.f);
    o.z = fmaxf(fmaf(di, acc.z, b4.z), 0.f);
    o.w = fmaxf(fmaf(di, acc.w, b4.w), 0.f);
    *(float4*)(out + (size_t)d * H1v + fo) = o;
}

template <int D, bool RELU>
__global__ __launch_bounds__(256) void k_agg_small(const float* __restrict__ h,
                                                   const int* __restrict__ rp,
                                                   const int* __restrict__ srcs,
                                                   const float* __restrict__ dinv,
                                                   const float* __restrict__ bias,
                                                   float* __restrict__ out) {
    constexpr int PER = 256 / D;
    const int sub = threadIdx.x / D;
    const int f = threadIdx.x % D;
    const int d = blockIdx.x * PER + sub;
    if (d >= N) return;
    const int beg = rp[d], end = rp[d + 1];
    float acc = h[(size_t)d * D + f];  // self-loop
    int j = beg;
    for (; j + 3 < end; j += 4) {
        float v0 = h[(size_t)srcs[j] * D + f];
        float v1 = h[(size_t)srcs[j + 1] * D + f];
        float v2 = h[(size_t)srcs[j + 2] * D + f];
        float v3 = h[(size_t)srcs[j + 3] * D + f];
        acc += v0 + v1 + v2 + v3;
    }
    for (; j < end; ++j) acc += h[(size_t)srcs[j] * D + f];
    float v = fmaf(dinv[d], acc, bias[f]);
    if (RELU) v = fmaxf(v, 0.f);
    out[(size_t)d * D + f] = v;
}

// ---------------- launch ----------------

extern "C" void kernel_launch(void* const* d_in, const int* in_sizes, int n_in,
                              void* d_out, int out_size, void* d_ws, size_t ws_size,
                              hipStream_t stream) {
    const float* x  = (const float*)d_in[0];
    const int*   ei = (const int*)d_in[1];
    const float* W1 = (const float*)d_in[2];
    const float* b1 = (const float*)d_in[3];
    const float* W2 = (const float*)d_in[4];
    const float* b2 = (const float*)d_in[5];
    const float* W3 = (const float*)d_in[6];
    const float* b3 = (const float*)d_in[7];
    const int* src = ei;       // edge_index[0]
    const int* dst = ei + E;   // edge_index[1]
    float* out = (float*)d_out;

    // Workspace layout (bytes):
    // [0       ] dinv    float[50000]
    // [0x40000 ] cnt/rp  int[50001]   (in-place scan)
    // [0x80000 ] cursor  int[50000]
    // [0xC0000 ] srcs    int[800000]
    // [4 MiB   ] Wsplit  ushort[262144]  (512 KB, bf16 hi/lo frag layout)
    // [5 MiB   ] hbuf    float[N*256]    (51.2 MB)
    // [5MiB+51.2MB] abuf float[N*256]    (51.2 MB)   total ~107.6 MB
    char* ws = (char*)d_ws;
    float* dinv   = (float*)ws;
    int*   cnt    = (int*)(ws + 0x40000);
    int*   rp     = cnt;
    int*   cursor = (int*)(ws + 0x80000);
    int*   srcs   = (int*)(ws + 0xC0000);
    unsigned short* wsplit = (unsigned short*)(ws + (size_t)4 * 1024 * 1024);
    float* hbuf   = (float*)(ws + (size_t)5 * 1024 * 1024);
    float* abuf   = (float*)(ws + (size_t)5 * 1024 * 1024 + (size_t)N * H1v * sizeof(float));

    hipMemsetAsync(cnt, 0, (N + 1) * sizeof(int), stream);
    k_hist<<<(E + 255) / 256, 256, 0, stream>>>(dst, cnt);
    k_dinv<<<(N + 255) / 256, 256, 0, stream>>>(cnt, dinv);
    k_scan<<<1, 1024, 0, stream>>>(cnt, rp, cursor);
    k_permute<<<(E + 255) / 256, 256, 0, stream>>>(src, dst, cursor, srcs);
    k_wsplit<<<64, 256, 0, stream>>>(W1, wsplit);

    // ---- layer 1: 512 -> 256 (MFMA), ReLU ----
    dim3 g1((N + 127) / 128, 2);
    k_gemm1_mfma<<<g1, 256, 0, stream>>>(x, wsplit, dinv, hbuf);
    k_agg_d256<<<(N + 3) / 4, 256, 0, stream>>>(hbuf, rp, srcs, dinv, b1, abuf);

    // ---- layer 2: 256 -> 32, ReLU ----
    k_gemm2<<<N / 8, 256, 0, stream>>>(abuf, W2, dinv, hbuf);
    k_agg_small<32, true><<<N / 8, 256, 0, stream>>>(hbuf, rp, srcs, dinv, b2, abuf);

    // ---- layer 3: 32 -> 16, no ReLU ----
    k_gemm3<<<N / 16, 256, 0, stream>>>(abuf, W3, dinv, hbuf);
    k_agg_small<16, false><<<N / 16, 256, 0, stream>>>(hbuf, rp, srcs, dinv, b3, out);
}

// Round 4
// 561.594 us; speedup vs baseline: 2.2839x; 1.0691x over previous
//
#include <hip/hip_runtime.h>

// Problem constants (from reference)
constexpr int N   = 50000;
constexpr int E   = 800000;
constexpr int FIN = 512;
constexpr int H1v = 256;
constexpr int H2v = 32;
constexpr int Cv  = 16;

typedef __attribute__((ext_vector_type(8))) short short8;            // 8 bf16 (MFMA frag)
typedef __attribute__((ext_vector_type(4))) float f32x4;             // MFMA C/D frag
typedef __attribute__((ext_vector_type(4))) unsigned short us4;      // 4 bf16

// fp32 -> bf16 round-to-nearest-even, and back
__device__ inline unsigned short f2bf(float f) {
    unsigned u = __float_as_uint(f);
    return (unsigned short)((u + 0x7FFFu + ((u >> 16) & 1u)) >> 16);
}
__device__ inline float bf2f(unsigned short b) { return __uint_as_float(((unsigned)b) << 16); }

// ---------------- degree histogram / CSR build ----------------

__global__ __launch_bounds__(256) void k_hist(const int* __restrict__ dst,
                                              int* __restrict__ cnt) {
    int e = blockIdx.x * 256 + threadIdx.x;
    if (e < E) atomicAdd(&cnt[dst[e]], 1);
}

// Single-block exclusive scan over 50000 counts -> row_ptr, cursor, and dinv.
// In-place safe: each thread reads its chunk into registers before writing.
__global__ __launch_bounds__(1024) void k_scan(const int* __restrict__ cnt,
                                               int* __restrict__ row_ptr,
                                               int* __restrict__ cursor,
                                               float* __restrict__ dinv) {
    __shared__ int sums[1024];
    const int t = threadIdx.x;
    constexpr int CH = 49;  // 1024*49 = 50176 >= N
    const int base = t * CH;
    int vals[CH];
    int local = 0;
#pragma unroll
    for (int i = 0; i < CH; ++i) {
        int idx = base + i;
        int v = (idx < N) ? cnt[idx] : 0;
        vals[i] = v;
        local += v;
    }
    sums[t] = local;
    __syncthreads();
    for (int off = 1; off < 1024; off <<= 1) {
        int v = (t >= off) ? sums[t - off] : 0;
        __syncthreads();
        sums[t] += v;
        __syncthreads();
    }
    int run = (t == 0) ? 0 : sums[t - 1];
#pragma unroll
    for (int i = 0; i < CH; ++i) {
        int idx = base + i;
        if (idx < N) {
            row_ptr[idx] = run;
            cursor[idx] = run;
            dinv[idx] = rsqrtf(1.0f + (float)vals[i]);  // +1 self-loop
        }
        run += vals[i];
    }
    if (t == 1023) row_ptr[N] = run;  // == E
}

__global__ __launch_bounds__(256) void k_permute(const int* __restrict__ src,
                                                 const int* __restrict__ dst,
                                                 int* __restrict__ cursor,
                                                 int* __restrict__ srcs) {
    int e = blockIdx.x * 256 + threadIdx.x;
    if (e < E) {
        int pos = atomicAdd(&cursor[dst[e]], 1);
        srcs[pos] = src[e];
    }
}

// ---------------- W1 split: fp32 [512][256] -> bf16 hi/lo in MFMA B-frag layout ----
// Tile (ktg 0..15, ntg 0..15): B[k][n], k = ktg*32 + (l>>4)*8 + j, n = ntg*16 + (l&15).
// Storage (ushorts): tile base = ((ktg*16+ntg)*2)*512; hi at +l*8, lo at +512+l*8.

__global__ __launch_bounds__(256) void k_wsplit(const float* __restrict__ W,
                                                unsigned short* __restrict__ Wf) {
    int t = blockIdx.x * 256 + threadIdx.x;  // 0..16383
    int l = t & 63, nt = (t >> 6) & 15, kt = t >> 10;
    int n = nt * 16 + (l & 15);
    int kb = kt * 32 + (l >> 4) * 8;
    short8 h8, l8;
#pragma unroll
    for (int j = 0; j < 8; ++j) {
        float w = W[(size_t)(kb + j) * H1v + n];
        unsigned short h = f2bf(w);
        h8[j] = (short)h;
        l8[j] = (short)f2bf(w - bf2f(h));
    }
    size_t base = ((size_t)(kt * 16 + nt) * 2) * 512 + (size_t)l * 8;
    *(short8*)(Wf + base) = h8;
    *(short8*)(Wf + base + 512) = l8;
}

// ---------------- GEMM 1 (MFMA, split-bf16 x3): [N,512] @ [512,256], *dinv, bf16 out

__global__ __launch_bounds__(256, 2) void k_gemm1_mfma(const float* __restrict__ X,
                                                       const unsigned short* __restrict__ Wf,
                                                       const float* __restrict__ dinv,
                                                       unsigned short* __restrict__ Hout) {
    __shared__ char lds[65536];
    const int tid = threadIdx.x;
    const int w = tid >> 6, l = tid & 63;
    const int wr = w >> 1, wc = w & 1;
    const int row0 = blockIdx.x * 128;
    const int colb = blockIdx.y;

    const int arow_l = tid >> 1;
    const int akh = tid & 1;
    const int arow = row0 + arow_l;
    const bool aok = arow < N;
    const float* aptr = X + (size_t)arow * FIN + akh * 32;
    const int art = arow_l >> 4, am = arow_l & 15;

    f32x4 acc[4][4];
#pragma unroll
    for (int i = 0; i < 4; ++i)
#pragma unroll
        for (int j = 0; j < 4; ++j) acc[i][j] = (f32x4)0.f;

    float4 xv[8];
#pragma unroll
    for (int g = 0; g < 8; ++g)
        xv[g] = aok ? *(const float4*)(aptr + g * 4) : make_float4(0.f, 0.f, 0.f, 0.f);

    for (int it = 0; it < 8; ++it) {  // 512 / 64
        __syncthreads();  // waves done reading LDS from previous iter

        // ---- B first: 32 chunks of 1 KB async global->LDS (overlaps A convert) ----
#pragma unroll
        for (int c = 0; c < 8; ++c) {
            int chunk = w * 8 + c;
            int plane = chunk & 1, nt = (chunk >> 1) & 7, kt = chunk >> 4;
            int ktg = it * 2 + kt, ntg = colb * 8 + nt;
            const unsigned short* gp = Wf + ((size_t)(ktg * 16 + ntg) * 2 + plane) * 512 + (size_t)l * 8;
            char* lp = lds + 32768 + ((kt * 8 + nt) * 2 + plane) * 1024 + l * 16;
            __builtin_amdgcn_global_load_lds(
                (const __attribute__((address_space(1))) unsigned int*)gp,
                (__attribute__((address_space(3))) unsigned int*)lp, 16, 0, 0);
        }

        // ---- A: convert 32 fp32 -> bf16 hi/lo, write frag entries ----
#pragma unroll
        for (int g = 0; g < 4; ++g) {
            float xs[8] = {xv[2*g].x, xv[2*g].y, xv[2*g].z, xv[2*g].w,
                           xv[2*g+1].x, xv[2*g+1].y, xv[2*g+1].z, xv[2*g+1].w};
            short8 h8, l8;
#pragma unroll
            for (int j = 0; j < 8; ++j) {
                unsigned short h = f2bf(xs[j]);
                h8[j] = (short)h;
                l8[j] = (short)f2bf(xs[j] - bf2f(h));
            }
            char* pa = lds + ((akh * 8 + art) * 2) * 1024 + (g * 16 + am) * 16;
            *(short8*)pa = h8;
            *(short8*)(pa + 1024) = l8;
        }
        __syncthreads();  // implies vmcnt(0): B staged, A visible

        // prefetch next iter's X while MFMAs run
        if (it < 7) {
#pragma unroll
            for (int g = 0; g < 8; ++g)
                xv[g] = aok ? *(const float4*)(aptr + (it + 1) * 64 + g * 4)
                            : make_float4(0.f, 0.f, 0.f, 0.f);
        }

        // ---- MFMA: 2 k-tiles of K=32, 4x4 16x16 tiles, 3 splits ----
#pragma unroll
        for (int kt = 0; kt < 2; ++kt) {
            short8 Ah[4], Al[4], Bh[4], Bl[4];
#pragma unroll
            for (int i = 0; i < 4; ++i) {
                char* p = lds + ((kt * 8 + wr * 4 + i) * 2) * 1024 + l * 16;
                Ah[i] = *(short8*)p;
                Al[i] = *(short8*)(p + 1024);
            }
#pragma unroll
            for (int j = 0; j < 4; ++j) {
                char* p = lds + 32768 + ((kt * 8 + wc * 4 + j) * 2) * 1024 + l * 16;
                Bh[j] = *(short8*)p;
                Bl[j] = *(short8*)(p + 1024);
            }
#pragma unroll
            for (int i = 0; i < 4; ++i)
#pragma unroll
                for (int j = 0; j < 4; ++j) {
                    acc[i][j] = __builtin_amdgcn_mfma_f32_16x16x32_bf16(Ah[i], Bh[j], acc[i][j], 0, 0, 0);
                    acc[i][j] = __builtin_amdgcn_mfma_f32_16x16x32_bf16(Ah[i], Bl[j], acc[i][j], 0, 0, 0);
                    acc[i][j] = __builtin_amdgcn_mfma_f32_16x16x32_bf16(Al[i], Bh[j], acc[i][j], 0, 0, 0);
                }
        }
    }

    // ---- epilogue: C row = (l>>4)*4 + reg, col = l&15 ; *dinv[row], store bf16 ----
    const int col0 = colb * 128;
#pragma unroll
    for (int i = 0; i < 4; ++i) {
        int rbase = row0 + (wr * 4 + i) * 16 + (l >> 4) * 4;
        float dv[4];
        bool ok[4];
#pragma unroll
        for (int r = 0; r < 4; ++r) {
            int rr = rbase + r;
            ok[r] = rr < N;
            dv[r] = ok[r] ? dinv[rr] : 0.f;
        }
#pragma unroll
        for (int j = 0; j < 4; ++j) {
            int col = col0 + (wc * 4 + j) * 16 + (l & 15);
#pragma unroll
            for (int r = 0; r < 4; ++r)
                if (ok[r]) Hout[(size_t)(rbase + r) * H1v + col] = f2bf(acc[i][j][r] * dv[r]);
        }
    }
}

// ---------------- GEMM 2: [N,256] @ [256,32] fp32 in, *dinv, bf16 out ----------------

__global__ __launch_bounds__(256) void k_gemm2(const float* __restrict__ A,
                                               const float* __restrict__ W,
                                               const float* __restrict__ dinv,
                                               unsigned short* __restrict__ Hout) {
    __shared__ float Ws[H1v * H2v];  // 32 KB
    const int tid = threadIdx.x;
#pragma unroll
    for (int i = 0; i < 8; ++i) {
        int off = tid * 4 + i * 1024;
        *(float4*)(&Ws[off]) = *(const float4*)(W + off);
    }
    __syncthreads();

    const int row = blockIdx.x * 8 + (tid >> 5);
    const int col = tid & 31;
    if (row >= N) return;
    const float* arow = A + (size_t)row * H1v;
    float sum = 0.f;
#pragma unroll 4
    for (int k = 0; k < H1v; k += 4) {
        float4 a4 = *(const float4*)(arow + k);
        sum = fmaf(a4.x, Ws[(k + 0) * H2v + col], sum);
        sum = fmaf(a4.y, Ws[(k + 1) * H2v + col], sum);
        sum = fmaf(a4.z, Ws[(k + 2) * H2v + col], sum);
        sum = fmaf(a4.w, Ws[(k + 3) * H2v + col], sum);
    }
    Hout[(size_t)row * H2v + col] = f2bf(sum * dinv[row]);
}

// ---------------- GEMM 3: [N,32] @ [32,16] fp32 in, *dinv, bf16 out ----------------

__global__ __launch_bounds__(256) void k_gemm3(const float* __restrict__ A,
                                               const float* __restrict__ W,
                                               const float* __restrict__ dinv,
                                               unsigned short* __restrict__ Hout) {
    __shared__ float Ws[H2v * Cv];
    const int tid = threadIdx.x;
    *(float2*)(&Ws[tid * 2]) = *(const float2*)(W + tid * 2);
    __syncthreads();

    const int row = blockIdx.x * 16 + (tid >> 4);
    const int col = tid & 15;
    if (row >= N) return;
    const float* arow = A + (size_t)row * H2v;
    float sum = 0.f;
#pragma unroll
    for (int k = 0; k < H2v; ++k) sum = fmaf(arow[k], Ws[k * Cv + col], sum);
    Hout[(size_t)row * Cv + col] = f2bf(sum * dinv[row]);
}

// ---------------- CSR aggregation (atomic-free, bf16 messages, fp32 accum) -------
// h holds bf16 h'[i] = dinv[i]*(a@W)[i].  out[d] = dinv[d]*(sum h'[s] + h'[d]) + b

__global__ __launch_bounds__(256) void k_agg_d256(const unsigned short* __restrict__ h,
                                                  const int* __restrict__ rp,
                                                  const int* __restrict__ srcs,
                                                  const float* __restrict__ dinv,
                                                  const float* __restrict__ bias,
                                                  float* __restrict__ out) {
    const int wave = threadIdx.x >> 6;
    const int lane = threadIdx.x & 63;
    const int d = blockIdx.x * 4 + wave;
    if (d >= N) return;
    const int beg = rp[d], end = rp[d + 1];
    const int fo = lane * 4;
    us4 sv = *(const us4*)(h + (size_t)d * H1v + fo);  // self-loop
    float ax = bf2f(sv.x), ay = bf2f(sv.y), az = bf2f(sv.z), aw = bf2f(sv.w);
    int j = beg;
    for (; j + 3 < end; j += 4) {  // 4 independent gathers in flight
        int s0 = srcs[j], s1 = srcs[j + 1], s2 = srcs[j + 2], s3 = srcs[j + 3];
        us4 v0 = *(const us4*)(h + (size_t)s0 * H1v + fo);
        us4 v1 = *(const us4*)(h + (size_t)s1 * H1v + fo);
        us4 v2 = *(const us4*)(h + (size_t)s2 * H1v + fo);
        us4 v3 = *(const us4*)(h + (size_t)s3 * H1v + fo);
        ax += bf2f(v0.x) + bf2f(v1.x) + bf2f(v2.x) + bf2f(v3.x);
        ay += bf2f(v0.y) + bf2f(v1.y) + bf2f(v2.y) + bf2f(v3.y);
        az += bf2f(v0.z) + bf2f(v1.z) + bf2f(v2.z) + bf2f(v3.z);
        aw += bf2f(v0.w) + bf2f(v1.w) + bf2f(v2.w) + bf2f(v3.w);
    }
    for (; j < end; ++j) {
        us4 v = *(const us4*)(h + (size_t)srcs[j] * H1v + fo);
        ax += bf2f(v.x); ay += bf2f(v.y); az += bf2f(v.z); aw += bf2f(v.w);
    }
    const float di = dinv[d];
    const float4 b4 = *(const float4*)(bias + fo);
    float4 o;
    o.x = fmaxf(fmaf(di, ax, b4.x), 0.f);
    o.y = fmaxf(fmaf(di, ay, b4.y), 0.f);
    o.z = fmaxf(fmaf(di, az, b4.z), 0.f);
    o.w = fmaxf(fmaf(di, aw, b4.w), 0.f);
    *(float4*)(out + (size_t)d * H1v + fo) = o;
}

template <int D, bool RELU>
__global__ __launch_bounds__(256) void k_agg_small(const unsigned short* __restrict__ h,
                                                   const int* __restrict__ rp,
                                                   const int* __restrict__ srcs,
                                                   const float* __restrict__ dinv,
                                                   const float* __restrict__ bias,
                                                   float* __restrict__ out) {
    constexpr int PER = 256 / D;
    const int sub = threadIdx.x / D;
    const int f = threadIdx.x % D;
    const int d = blockIdx.x * PER + sub;
    if (d >= N) return;
    const int beg = rp[d], end = rp[d + 1];
    float acc = bf2f(h[(size_t)d * D + f]);  // self-loop
    int j = beg;
    for (; j + 3 < end; j += 4) {
        float v0 = bf2f(h[(size_t)srcs[j] * D + f]);
        float v1 = bf2f(h[(size_t)srcs[j + 1] * D + f]);
        float v2 = bf2f(h[(size_t)srcs[j + 2] * D + f]);
        float v3 = bf2f(h[(size_t)srcs[j + 3] * D + f]);
        acc += v0 + v1 + v2 + v3;
    }
    for (; j < end; ++j) acc += bf2f(h[(size_t)srcs[j] * D + f]);
    float v = fmaf(dinv[d], acc, bias[f]);
    if (RELU) v = fmaxf(v, 0.f);
    out[(size_t)d * D + f] = v;
}

// ---------------- launch ----------------

extern "C" void kernel_launch(void* const* d_in, const int* in_sizes, int n_in,
                              void* d_out, int out_size, void* d_ws, size_t ws_size,
                              hipStream_t stream) {
    const float* x  = (const float*)d_in[0];
    const int*   ei = (const int*)d_in[1];
    const float* W1 = (const float*)d_in[2];
    const float* b1 = (const float*)d_in[3];
    const float* W2 = (const float*)d_in[4];
    const float* b2 = (const float*)d_in[5];
    const float* W3 = (const float*)d_in[6];
    const float* b3 = (const float*)d_in[7];
    const int* src = ei;       // edge_index[0]
    const int* dst = ei + E;   // edge_index[1]
    float* out = (float*)d_out;

    // Workspace layout (bytes):
    // [0       ] dinv    float[50000]
    // [0x40000 ] cnt/rp  int[50001]   (in-place scan)
    // [0x80000 ] cursor  int[50000]
    // [0xC0000 ] srcs    int[800000]
    // [4 MiB   ] Wsplit  ushort[262144]  (512 KB)
    // [5 MiB   ] h1 bf16 ushort[N*256]   (25.6 MB)
    // then      a1 fp32  float[N*256]    (51.2 MB)
    // then      h2 bf16  ushort[N*32]    (3.2 MB)
    // then      a2 fp32  float[N*32]     (6.4 MB)
    // then      h3 bf16  ushort[N*16]    (1.6 MB)   total ~93 MB
    char* ws = (char*)d_ws;
    float* dinv   = (float*)ws;
    int*   cnt    = (int*)(ws + 0x40000);
    int*   rp     = cnt;
    int*   cursor = (int*)(ws + 0x80000);
    int*   srcs   = (int*)(ws + 0xC0000);
    unsigned short* wsplit = (unsigned short*)(ws + (size_t)4 * 1024 * 1024);
    char* p = ws + (size_t)5 * 1024 * 1024;
    unsigned short* h1 = (unsigned short*)p; p += (size_t)N * H1v * sizeof(unsigned short);
    float*          a1 = (float*)p;          p += (size_t)N * H1v * sizeof(float);
    unsigned short* h2 = (unsigned short*)p; p += (size_t)N * H2v * sizeof(unsigned short);
    float*          a2 = (float*)p;          p += (size_t)N * H2v * sizeof(float);
    unsigned short* h3 = (unsigned short*)p;

    hipMemsetAsync(cnt, 0, (N + 1) * sizeof(int), stream);
    k_hist<<<(E + 255) / 256, 256, 0, stream>>>(dst, cnt);
    k_scan<<<1, 1024, 0, stream>>>(cnt, rp, cursor, dinv);
    k_permute<<<(E + 255) / 256, 256, 0, stream>>>(src, dst, cursor, srcs);
    k_wsplit<<<64, 256, 0, stream>>>(W1, wsplit);

    // ---- layer 1: 512 -> 256 (MFMA), ReLU ----
    dim3 g1((N + 127) / 128, 2);
    k_gemm1_mfma<<<g1, 256, 0, stream>>>(x, wsplit, dinv, h1);
    k_agg_d256<<<(N + 3) / 4, 256, 0, stream>>>(h1, rp, srcs, dinv, b1, a1);

    // ---- layer 2: 256 -> 32, ReLU ----
    k_gemm2<<<N / 8, 256, 0, stream>>>(a1, W2, dinv, h2);
    k_agg_small<32, true><<<N / 8, 256, 0, stream>>>(h2, rp, srcs, dinv, b2, a2);

    // ---- layer 3: 32 -> 16, no ReLU ----
    k_gemm3<<<N / 16, 256, 0, stream>>>(a2, W3, dinv, h3);
    k_agg_small<16, false><<<N / 16, 256, 0, stream>>>(h3, rp, srcs, dinv, b3, out);
}

// Round 5
// 466.979 us; speedup vs baseline: 2.7467x; 1.2026x over previous
//
#include <hip/hip_runtime.h>

// Problem constants (from reference)
constexpr int N   = 50000;
constexpr int E   = 800000;
constexpr int FIN = 512;
constexpr int H1v = 256;
constexpr int H2v = 32;
constexpr int Cv  = 16;

constexpr int NBLK = (N + 1023) / 1024;  // 49 scan blocks

typedef __attribute__((ext_vector_type(8))) short short8;            // 8 bf16 (MFMA frag)
typedef __attribute__((ext_vector_type(4))) float f32x4;             // MFMA C/D frag
typedef __attribute__((ext_vector_type(4))) unsigned short us4;      // 4 bf16

// fp32 -> bf16 round-to-nearest-even, and back
__device__ inline unsigned short f2bf(float f) {
    unsigned u = __float_as_uint(f);
    return (unsigned short)((u + 0x7FFFu + ((u >> 16) & 1u)) >> 16);
}
__device__ inline float bf2f(unsigned short b) { return __uint_as_float(((unsigned)b) << 16); }

// ---------------- degree histogram / CSR build ----------------

__global__ __launch_bounds__(256) void k_hist(const int* __restrict__ dst,
                                              int* __restrict__ cnt) {
    int e = blockIdx.x * 256 + threadIdx.x;
    if (e < E) atomicAdd(&cnt[dst[e]], 1);
}

// Phase 1: per-block (1024 elems) sums.
__global__ __launch_bounds__(256) void k_scan_part(const int* __restrict__ cnt,
                                                   int* __restrict__ bsum) {
    __shared__ int red[256];
    const int t = threadIdx.x;
    const int base = blockIdx.x * 1024 + t * 4;
    int s = 0;
#pragma unroll
    for (int i = 0; i < 4; ++i) {
        int idx = base + i;
        if (idx < N) s += cnt[idx];
    }
    red[t] = s;
    __syncthreads();
    for (int off = 128; off > 0; off >>= 1) {
        if (t < off) red[t] += red[t + off];
        __syncthreads();
    }
    if (t == 0) bsum[blockIdx.x] = red[0];
}

// Phase 2: one wave scans the 49 block sums.
__global__ __launch_bounds__(64) void k_scan_top(const int* __restrict__ bsum,
                                                 int* __restrict__ boff,
                                                 int* __restrict__ row_ptr) {
    const int l = threadIdx.x;
    int orig = (l < NBLK) ? bsum[l] : 0;
    int v = orig;
    for (int off = 1; off < 64; off <<= 1) {
        int u = __shfl_up(v, off, 64);
        if (l >= off) v += u;
    }
    if (l < NBLK) boff[l] = v - orig;          // exclusive block offset
    if (l == NBLK - 1) row_ptr[N] = v;          // total == E
}

// Phase 3: block-local scan + block offset -> row_ptr, cursor, dinv.
// In-place safe vs cnt: each block reads only its own disjoint 1024-range
// into registers before any write.
__global__ __launch_bounds__(256) void k_scan_final(const int* __restrict__ cnt,
                                                    const int* __restrict__ boff,
                                                    int* __restrict__ row_ptr,
                                                    int* __restrict__ cursor,
                                                    float* __restrict__ dinv) {
    __shared__ int sums[256];
    const int t = threadIdx.x;
    const int base = blockIdx.x * 1024 + t * 4;
    int v[4];
    int local = 0;
#pragma unroll
    for (int i = 0; i < 4; ++i) {
        int idx = base + i;
        v[i] = (idx < N) ? cnt[idx] : 0;
        local += v[i];
    }
    sums[t] = local;
    __syncthreads();
    for (int off = 1; off < 256; off <<= 1) {
        int u = (t >= off) ? sums[t - off] : 0;
        __syncthreads();
        sums[t] += u;
        __syncthreads();
    }
    int run = boff[blockIdx.x] + sums[t] - local;  // exclusive thread offset
#pragma unroll
    for (int i = 0; i < 4; ++i) {
        int idx = base + i;
        if (idx < N) {
            row_ptr[idx] = run;
            cursor[idx] = run;
            dinv[idx] = rsqrtf(1.0f + (float)v[i]);  // +1 self-loop
        }
        run += v[i];
    }
}

__global__ __launch_bounds__(256) void k_permute(const int* __restrict__ src,
                                                 const int* __restrict__ dst,
                                                 int* __restrict__ cursor,
                                                 int* __restrict__ srcs) {
    int e = blockIdx.x * 256 + threadIdx.x;
    if (e < E) {
        int pos = atomicAdd(&cursor[dst[e]], 1);
        srcs[pos] = src[e];
    }
}

// ---------------- W1 split: fp32 [512][256] -> bf16 hi/lo in MFMA B-frag layout ----
// Tile (ktg 0..15, ntg 0..15): B[k][n], k = ktg*32 + (l>>4)*8 + j, n = ntg*16 + (l&15).
// Storage (ushorts): tile base = ((ktg*16+ntg)*2)*512; hi at +l*8, lo at +512+l*8.

__global__ __launch_bounds__(256) void k_wsplit(const float* __restrict__ W,
                                                unsigned short* __restrict__ Wf) {
    int t = blockIdx.x * 256 + threadIdx.x;  // 0..16383
    int l = t & 63, nt = (t >> 6) & 15, kt = t >> 10;
    int n = nt * 16 + (l & 15);
    int kb = kt * 32 + (l >> 4) * 8;
    short8 h8, l8;
#pragma unroll
    for (int j = 0; j < 8; ++j) {
        float w = W[(size_t)(kb + j) * H1v + n];
        unsigned short h = f2bf(w);
        h8[j] = (short)h;
        l8[j] = (short)f2bf(w - bf2f(h));
    }
    size_t base = ((size_t)(kt * 16 + nt) * 2) * 512 + (size_t)l * 8;
    *(short8*)(Wf + base) = h8;
    *(short8*)(Wf + base + 512) = l8;
}

// ---------------- GEMM 1 (MFMA, split-bf16 x3): [N,512] @ [512,256], *dinv, bf16 out

__global__ __launch_bounds__(256, 2) void k_gemm1_mfma(const float* __restrict__ X,
                                                       const unsigned short* __restrict__ Wf,
                                                       const float* __restrict__ dinv,
                                                       unsigned short* __restrict__ Hout) {
    __shared__ char lds[65536];
    const int tid = threadIdx.x;
    const int w = tid >> 6, l = tid & 63;
    const int wr = w >> 1, wc = w & 1;
    const int row0 = blockIdx.x * 128;
    const int colb = blockIdx.y;

    const int arow_l = tid >> 1;
    const int akh = tid & 1;
    const int arow = row0 + arow_l;
    const bool aok = arow < N;
    const float* aptr = X + (size_t)arow * FIN + akh * 32;
    const int art = arow_l >> 4, am = arow_l & 15;

    f32x4 acc[4][4];
#pragma unroll
    for (int i = 0; i < 4; ++i)
#pragma unroll
        for (int j = 0; j < 4; ++j) acc[i][j] = (f32x4)0.f;

    float4 xv[8];
#pragma unroll
    for (int g = 0; g < 8; ++g)
        xv[g] = aok ? *(const float4*)(aptr + g * 4) : make_float4(0.f, 0.f, 0.f, 0.f);

    for (int it = 0; it < 8; ++it) {  // 512 / 64
        __syncthreads();  // waves done reading LDS from previous iter

        // ---- B first: 32 chunks of 1 KB async global->LDS (overlaps A convert) ----
#pragma unroll
        for (int c = 0; c < 8; ++c) {
            int chunk = w * 8 + c;
            int plane = chunk & 1, nt = (chunk >> 1) & 7, kt = chunk >> 4;
            int ktg = it * 2 + kt, ntg = colb * 8 + nt;
            const unsigned short* gp = Wf + ((size_t)(ktg * 16 + ntg) * 2 + plane) * 512 + (size_t)l * 8;
            char* lp = lds + 32768 + ((kt * 8 + nt) * 2 + plane) * 1024 + l * 16;
            __builtin_amdgcn_global_load_lds(
                (const __attribute__((address_space(1))) unsigned int*)gp,
                (__attribute__((address_space(3))) unsigned int*)lp, 16, 0, 0);
        }

        // ---- A: convert 32 fp32 -> bf16 hi/lo, write frag entries ----
#pragma unroll
        for (int g = 0; g < 4; ++g) {
            float xs[8] = {xv[2*g].x, xv[2*g].y, xv[2*g].z, xv[2*g].w,
                           xv[2*g+1].x, xv[2*g+1].y, xv[2*g+1].z, xv[2*g+1].w};
            short8 h8, l8;
#pragma unroll
            for (int j = 0; j < 8; ++j) {
                unsigned short h = f2bf(xs[j]);
                h8[j] = (short)h;
                l8[j] = (short)f2bf(xs[j] - bf2f(h));
            }
            char* pa = lds + ((akh * 8 + art) * 2) * 1024 + (g * 16 + am) * 16;
            *(short8*)pa = h8;
            *(short8*)(pa + 1024) = l8;
        }
        __syncthreads();  // implies vmcnt(0): B staged, A visible

        // prefetch next iter's X while MFMAs run
        if (it < 7) {
#pragma unroll
            for (int g = 0; g < 8; ++g)
                xv[g] = aok ? *(const float4*)(aptr + (it + 1) * 64 + g * 4)
                            : make_float4(0.f, 0.f, 0.f, 0.f);
        }

        // ---- MFMA: 2 k-tiles of K=32, 4x4 16x16 tiles, 3 splits ----
#pragma unroll
        for (int kt = 0; kt < 2; ++kt) {
            short8 Ah[4], Al[4], Bh[4], Bl[4];
#pragma unroll
            for (int i = 0; i < 4; ++i) {
                char* p = lds + ((kt * 8 + wr * 4 + i) * 2) * 1024 + l * 16;
                Ah[i] = *(short8*)p;
                Al[i] = *(short8*)(p + 1024);
            }
#pragma unroll
            for (int j = 0; j < 4; ++j) {
                char* p = lds + 32768 + ((kt * 8 + wc * 4 + j) * 2) * 1024 + l * 16;
                Bh[j] = *(short8*)p;
                Bl[j] = *(short8*)(p + 1024);
            }
#pragma unroll
            for (int i = 0; i < 4; ++i)
#pragma unroll
                for (int j = 0; j < 4; ++j) {
                    acc[i][j] = __builtin_amdgcn_mfma_f32_16x16x32_bf16(Ah[i], Bh[j], acc[i][j], 0, 0, 0);
                    acc[i][j] = __builtin_amdgcn_mfma_f32_16x16x32_bf16(Ah[i], Bl[j], acc[i][j], 0, 0, 0);
                    acc[i][j] = __builtin_amdgcn_mfma_f32_16x16x32_bf16(Al[i], Bh[j], acc[i][j], 0, 0, 0);
                }
        }
    }

    // ---- epilogue: C row = (l>>4)*4 + reg, col = l&15 ; *dinv[row], store bf16 ----
    const int col0 = colb * 128;
#pragma unroll
    for (int i = 0; i < 4; ++i) {
        int rbase = row0 + (wr * 4 + i) * 16 + (l >> 4) * 4;
        float dv[4];
        bool ok[4];
#pragma unroll
        for (int r = 0; r < 4; ++r) {
            int rr = rbase + r;
            ok[r] = rr < N;
            dv[r] = ok[r] ? dinv[rr] : 0.f;
        }
#pragma unroll
        for (int j = 0; j < 4; ++j) {
            int col = col0 + (wc * 4 + j) * 16 + (l & 15);
#pragma unroll
            for (int r = 0; r < 4; ++r)
                if (ok[r]) Hout[(size_t)(rbase + r) * H1v + col] = f2bf(acc[i][j][r] * dv[r]);
        }
    }
}

// ---------------- GEMM 2: [N,256] @ [256,32] fp32 in, *dinv, bf16 out ----------------

__global__ __launch_bounds__(256) void k_gemm2(const float* __restrict__ A,
                                               const float* __restrict__ W,
                                               const float* __restrict__ dinv,
                                               unsigned short* __restrict__ Hout) {
    __shared__ float Ws[H1v * H2v];  // 32 KB
    const int tid = threadIdx.x;
#pragma unroll
    for (int i = 0; i < 8; ++i) {
        int off = tid * 4 + i * 1024;
        *(float4*)(&Ws[off]) = *(const float4*)(W + off);
    }
    __syncthreads();

    const int row = blockIdx.x * 8 + (tid >> 5);
    const int col = tid & 31;
    if (row >= N) return;
    const float* arow = A + (size_t)row * H1v;
    float sum = 0.f;
#pragma unroll 4
    for (int k = 0; k < H1v; k += 4) {
        float4 a4 = *(const float4*)(arow + k);
        sum = fmaf(a4.x, Ws[(k + 0) * H2v + col], sum);
        sum = fmaf(a4.y, Ws[(k + 1) * H2v + col], sum);
        sum = fmaf(a4.z, Ws[(k + 2) * H2v + col], sum);
        sum = fmaf(a4.w, Ws[(k + 3) * H2v + col], sum);
    }
    Hout[(size_t)row * H2v + col] = f2bf(sum * dinv[row]);
}

// ---------------- GEMM 3: [N,32] @ [32,16] fp32 in, *dinv, bf16 out ----------------

__global__ __launch_bounds__(256) void k_gemm3(const float* __restrict__ A,
                                               const float* __restrict__ W,
                                               const float* __restrict__ dinv,
                                               unsigned short* __restrict__ Hout) {
    __shared__ float Ws[H2v * Cv];
    const int tid = threadIdx.x;
    *(float2*)(&Ws[tid * 2]) = *(const float2*)(W + tid * 2);
    __syncthreads();

    const int row = blockIdx.x * 16 + (tid >> 4);
    const int col = tid & 15;
    if (row >= N) return;
    const float* arow = A + (size_t)row * H2v;
    float sum = 0.f;
#pragma unroll
    for (int k = 0; k < H2v; ++k) sum = fmaf(arow[k], Ws[k * Cv + col], sum);
    Hout[(size_t)row * Cv + col] = f2bf(sum * dinv[row]);
}

// ---------------- CSR aggregation (atomic-free, bf16 messages, fp32 accum) -------
// h holds bf16 h'[i] = dinv[i]*(a@W)[i].  out[d] = dinv[d]*(sum h'[s] + h'[d]) + b

__global__ __launch_bounds__(256) void k_agg_d256(const unsigned short* __restrict__ h,
                                                  const int* __restrict__ rp,
                                                  const int* __restrict__ srcs,
                                                  const float* __restrict__ dinv,
                                                  const float* __restrict__ bias,
                                                  float* __restrict__ out) {
    const int wave = threadIdx.x >> 6;
    const int lane = threadIdx.x & 63;
    const int d = blockIdx.x * 4 + wave;
    if (d >= N) return;
    const int beg = rp[d], end = rp[d + 1];
    const int fo = lane * 4;
    us4 sv = *(const us4*)(h + (size_t)d * H1v + fo);  // self-loop
    float ax = bf2f(sv.x), ay = bf2f(sv.y), az = bf2f(sv.z), aw = bf2f(sv.w);
    int j = beg;
    for (; j + 3 < end; j += 4) {  // 4 independent gathers in flight
        int s0 = srcs[j], s1 = srcs[j + 1], s2 = srcs[j + 2], s3 = srcs[j + 3];
        us4 v0 = *(const us4*)(h + (size_t)s0 * H1v + fo);
        us4 v1 = *(const us4*)(h + (size_t)s1 * H1v + fo);
        us4 v2 = *(const us4*)(h + (size_t)s2 * H1v + fo);
        us4 v3 = *(const us4*)(h + (size_t)s3 * H1v + fo);
        ax += bf2f(v0.x) + bf2f(v1.x) + bf2f(v2.x) + bf2f(v3.x);
        ay += bf2f(v0.y) + bf2f(v1.y) + bf2f(v2.y) + bf2f(v3.y);
        az += bf2f(v0.z) + bf2f(v1.z) + bf2f(v2.z) + bf2f(v3.z);
        aw += bf2f(v0.w) + bf2f(v1.w) + bf2f(v2.w) + bf2f(v3.w);
    }
    for (; j < end; ++j) {
        us4 v = *(const us4*)(h + (size_t)srcs[j] * H1v + fo);
        ax += bf2f(v.x); ay += bf2f(v.y); az += bf2f(v.z); aw += bf2f(v.w);
    }
    const float di = dinv[d];
    const float4 b4 = *(const float4*)(bias + fo);
    float4 o;
    o.x = fmaxf(fmaf(di, ax, b4.x), 0.f);
    o.y = fmaxf(fmaf(di, ay, b4.y), 0.f);
    o.z = fmaxf(fmaf(di, az, b4.z), 0.f);
    o.w = fmaxf(fmaf(di, aw, b4.w), 0.f);
    *(float4*)(out + (size_t)d * H1v + fo) = o;
}

template <int D, bool RELU>
__global__ __launch_bounds__(256) void k_agg_small(const unsigned short* __restrict__ h,
                                                   const int* __restrict__ rp,
                                                   const int* __restrict__ srcs,
                                                   const float* __restrict__ dinv,
                                                   const float* __restrict__ bias,
                                                   float* __restrict__ out) {
    constexpr int PER = 256 / D;
    const int sub = threadIdx.x / D;
    const int f = threadIdx.x % D;
    const int d = blockIdx.x * PER + sub;
    if (d >= N) return;
    const int beg = rp[d], end = rp[d + 1];
    float acc = bf2f(h[(size_t)d * D + f]);  // self-loop
    int j = beg;
    for (; j + 3 < end; j += 4) {
        float v0 = bf2f(h[(size_t)srcs[j] * D + f]);
        float v1 = bf2f(h[(size_t)srcs[j + 1] * D + f]);
        float v2 = bf2f(h[(size_t)srcs[j + 2] * D + f]);
        float v3 = bf2f(h[(size_t)srcs[j + 3] * D + f]);
        acc += v0 + v1 + v2 + v3;
    }
    for (; j < end; ++j) acc += bf2f(h[(size_t)srcs[j] * D + f]);
    float v = fmaf(dinv[d], acc, bias[f]);
    if (RELU) v = fmaxf(v, 0.f);
    out[(size_t)d * D + f] = v;
}

// ---------------- launch ----------------

extern "C" void kernel_launch(void* const* d_in, const int* in_sizes, int n_in,
                              void* d_out, int out_size, void* d_ws, size_t ws_size,
                              hipStream_t stream) {
    const float* x  = (const float*)d_in[0];
    const int*   ei = (const int*)d_in[1];
    const float* W1 = (const float*)d_in[2];
    const float* b1 = (const float*)d_in[3];
    const float* W2 = (const float*)d_in[4];
    const float* b2 = (const float*)d_in[5];
    const float* W3 = (const float*)d_in[6];
    const float* b3 = (const float*)d_in[7];
    const int* src = ei;       // edge_index[0]
    const int* dst = ei + E;   // edge_index[1]
    float* out = (float*)d_out;

    // Workspace layout (bytes):
    // [0       ] dinv    float[50000]
    // [0x40000 ] cnt/rp  int[50001]   (in-place scan)
    // [0x80000 ] cursor  int[50000]   (ends 0xB0D40)
    // [0xB2000 ] bsum    int[49]
    // [0xB3000 ] boff    int[49]
    // [0xC0000 ] srcs    int[800000]
    // [4 MiB   ] Wsplit  ushort[262144]  (512 KB)
    // [5 MiB   ] h1 bf16, a1 fp32, h2 bf16, a2 fp32, h3 bf16   total ~93 MB
    char* ws = (char*)d_ws;
    float* dinv   = (float*)ws;
    int*   cnt    = (int*)(ws + 0x40000);
    int*   rp     = cnt;
    int*   cursor = (int*)(ws + 0x80000);
    int*   bsum   = (int*)(ws + 0xB2000);
    int*   boff   = (int*)(ws + 0xB3000);
    int*   srcs   = (int*)(ws + 0xC0000);
    unsigned short* wsplit = (unsigned short*)(ws + (size_t)4 * 1024 * 1024);
    char* p = ws + (size_t)5 * 1024 * 1024;
    unsigned short* h1 = (unsigned short*)p; p += (size_t)N * H1v * sizeof(unsigned short);
    float*          a1 = (float*)p;          p += (size_t)N * H1v * sizeof(float);
    unsigned short* h2 = (unsigned short*)p; p += (size_t)N * H2v * sizeof(unsigned short);
    float*          a2 = (float*)p;          p += (size_t)N * H2v * sizeof(float);
    unsigned short* h3 = (unsigned short*)p;

    hipMemsetAsync(cnt, 0, (N + 1) * sizeof(int), stream);
    k_hist<<<(E + 255) / 256, 256, 0, stream>>>(dst, cnt);
    k_scan_part<<<NBLK, 256, 0, stream>>>(cnt, bsum);
    k_scan_top<<<1, 64, 0, stream>>>(bsum, boff, rp);
    k_scan_final<<<NBLK, 256, 0, stream>>>(cnt, boff, rp, cursor, dinv);
    k_permute<<<(E + 255) / 256, 256, 0, stream>>>(src, dst, cursor, srcs);
    k_wsplit<<<64, 256, 0, stream>>>(W1, wsplit);

    // ---- layer 1: 512 -> 256 (MFMA), ReLU ----
    dim3 g1((N + 127) / 128, 2);
    k_gemm1_mfma<<<g1, 256, 0, stream>>>(x, wsplit, dinv, h1);
    k_agg_d256<<<(N + 3) / 4, 256, 0, stream>>>(h1, rp, srcs, dinv, b1, a1);

    // ---- layer 2: 256 -> 32, ReLU ----
    k_gemm2<<<N / 8, 256, 0, stream>>>(a1, W2, dinv, h2);
    k_agg_small<32, true><<<N / 8, 256, 0, stream>>>(h2, rp, srcs, dinv, b2, a2);

    // ---- layer 3: 32 -> 16, no ReLU ----
    k_gemm3<<<N / 16, 256, 0, stream>>>(a2, W3, dinv, h3);
    k_agg_small<16, false><<<N / 16, 256, 0, stream>>>(h3, rp, srcs, dinv, b3, out);
}